// Round 17
// baseline (182.606 us; speedup 1.0000x reference)
//
#include <hip/hip_runtime.h>
#include <stdint.h>

// Match numpy's unfused mul/add rounding everywhere (no FMA contraction).
#pragma clang fp contract(off)

typedef unsigned long long ull;

// Problem constants (B=16, H=W=64, A=9, stride 16, img 1024x1024)
#define NB 16
#define NA 9
#define HW 4096
#define NANCH (NA*HW)         // 36864
#define TOTAL (NB*NANCH)      // 589824
#define TOPN 2000
#define PADN 2048             // global box/area stride
#define SELPAD 3072           // candidate buffer per batch (LDS)
#define OUTN 300
#define HBITS 13
#define HBINS (1 << HBITS)    // 8192 LDS histogram bins
#define MNMS 384              // mask extent (scan ends ~310; exact fallback past it)

// exact: RN32(inter/u) > 0.7f  <=>  (double)inter >= MIDC*(double)u
// (HW-verified: absmax 0 in rounds 9-16.)
#define MIDC 0x1.666667p-1

// 9 base anchors (x1,y1,x2,y2), computed exactly per the numpy generator
__constant__ float c_ax1[9] = {-3.5f,-15.f,-38.f,  0.f, -8.f,-24.f,  2.5f, -3.f,-14.f};
__constant__ float c_ay1[9] = { 2.f,  -4.f,-16.f,  0.f, -8.f,-24.f, -3.f,-14.f,-36.f};
__constant__ float c_ax2[9] = {18.5f, 30.f, 53.f, 15.f, 23.f, 39.f, 12.5f, 18.f, 29.f};
__constant__ float c_ay2[9] = {13.f,  19.f, 31.f, 15.f, 23.f, 39.f, 18.f,  29.f, 51.f};

__device__ __forceinline__ void decode_box(int a, int x, int y,
    float d0, float d1, float d2, float d3,
    float& x1, float& y1, float& x2, float& y2) {
  float ax1 = c_ax1[a] + 16.f * (float)x;
  float ay1 = c_ay1[a] + 16.f * (float)y;
  float ax2 = c_ax2[a] + 16.f * (float)x;
  float ay2 = c_ay2[a] + 16.f * (float)y;
  float aw  = ax2 - ax1 + 1.f;
  float ah  = ay2 - ay1 + 1.f;
  float acx = ax1 + 0.5f * aw;
  float acy = ay1 + 0.5f * ah;
  float cx = d0 * aw + acx;
  float cy = d1 * ah + acy;
  float pw = expf(d2) * aw;
  float ph = expf(d3) * ah;
  x1 = cx - 0.5f * pw;
  y1 = cy - 0.5f * ph;
  x2 = cx + 0.5f * pw;
  y2 = cy + 0.5f * ph;
  x1 = fminf(fmaxf(x1, 0.f), 1023.f);
  y1 = fminf(fmaxf(y1, 0.f), 1023.f);
  x2 = fminf(fmaxf(x2, 0.f), 1023.f);
  y2 = fminf(fmaxf(y2, 0.f), 1023.f);
}

__device__ __forceinline__ uint32_t f2ord(float f) {
  uint32_t u = __float_as_uint(f);
  return (u & 0x80000000u) ? ~u : (u | 0x80000000u);
}
__device__ __forceinline__ float ord2f(uint32_t u) {
  return (u & 0x80000000u) ? __uint_as_float(u ^ 0x80000000u) : __uint_as_float(~u);
}

// Kernel 1: masked ordered score keys, 4 anchors/thread (float4 loads, uint4
// store, [b][a][pos] layout). Proven in round 16.
__global__ void k_score(const float* __restrict__ labels, const float* __restrict__ bbox,
                        uint32_t* __restrict__ keys) {
  int t4 = blockIdx.x * 256 + threadIdx.x;     // grid 576 -> t4 < TOTAL/4
  int p4 = t4 & 1023;                          // float4 index within (b,a) plane
  int pos = p4 << 2;
  int ba = t4 >> 10;                           // b*9 + a  (0..143)
  int a = ba % 9, b = ba / 9;
  float4 sc  = ((const float4*)(labels + ((b * 18 + 2 * a + 1) << 12)))[p4];
  const float* dpb = bbox + ((b * 36 + 4 * a) << 12);
  float4 d0v = ((const float4*)(dpb        ))[p4];
  float4 d1v = ((const float4*)(dpb +  4096))[p4];
  float4 d2v = ((const float4*)(dpb +  8192))[p4];
  float4 d3v = ((const float4*)(dpb + 12288))[p4];
  int y = pos >> 6, x0 = pos & 63;             // pos%4==0 -> never crosses row
  float scA[4] = { sc.x,  sc.y,  sc.z,  sc.w  };
  float d0A[4] = { d0v.x, d0v.y, d0v.z, d0v.w };
  float d1A[4] = { d1v.x, d1v.y, d1v.z, d1v.w };
  float d2A[4] = { d2v.x, d2v.y, d2v.z, d2v.w };
  float d3A[4] = { d3v.x, d3v.y, d3v.z, d3v.w };
  uint32_t kout[4];
#pragma unroll
  for (int k = 0; k < 4; ++k) {
    float x1, y1, x2, y2;
    decode_box(a, x0 + k, y, d0A[k], d1A[k], d2A[k], d3A[k], x1, y1, x2, y2);
    bool keep = (x2 - x1 + 1.f >= 16.f) && (y2 - y1 + 1.f >= 16.f);
    kout[k] = f2ord(keep ? scA[k] : -INFINITY);
  }
  ((uint4*)(keys + b * NANCH + (a << 12) + pos))[0] =
      make_uint4(kout[0], kout[1], kout[2], kout[3]);
}

// Kernel 2: everything else, one block per batch (16 x 1024), phases separated
// by __syncthreads only (no inter-block sync). hist -> threshold -> compact
// (LDS) -> rank+decode -> mask (ballot, LDS) -> branchless replicated-bitmap
// greedy scan -> kept enumeration -> output. ~85 KB LDS.
__global__ __launch_bounds__(1024) void k_fused(
    const uint32_t* __restrict__ keys, const float* __restrict__ bbox,
    float4* __restrict__ boxes, float* __restrict__ areas,
    float* __restrict__ selScore, float* __restrict__ out) {
  int b = blockIdx.x, tid = threadIdx.x;
  int wave = tid >> 6, lane = tid & 63;

  __shared__ uint32_t hist[HBINS];                       // 32 KB
  __shared__ ull      sel[SELPAD];                       // 24 KB
  __shared__ float sx1[MNMS], sy1[MNMS], sx2[MNMS], sy2[MNMS], sar2[MNMS]; // 7.5 KB
  __shared__ ull __attribute__((aligned(16))) mrow[MNMS][6];               // 18 KB
  __shared__ int      kidx[OUTN];
  __shared__ uint32_t wtot[16];
  __shared__ uint32_t sh_T, sh_cnt;
  __shared__ int      sh_c;

  // ---- P0: zero hist + mask rows ----
#pragma unroll
  for (int k = 0; k < HBINS / 1024; ++k) hist[k * 1024 + tid] = 0u;
  for (int k = tid; k < MNMS * 6; k += 1024) ((ull*)mrow)[k] = 0ull;
  if (tid == 0) { sh_T = 0u; sh_cnt = 0u; }
  __syncthreads();

  const uint4* kb4 = (const uint4*)(keys + b * NANCH);
  // ---- P1: histogram (positive keys only) ----
  for (int i4 = tid; i4 < NANCH / 4; i4 += 1024) {
    uint4 v = kb4[i4];
    if (v.x & 0x80000000u) atomicAdd(&hist[v.x >> (32 - HBITS)], 1u);
    if (v.y & 0x80000000u) atomicAdd(&hist[v.y >> (32 - HBITS)], 1u);
    if (v.z & 0x80000000u) atomicAdd(&hist[v.z >> (32 - HBITS)], 1u);
    if (v.w & 0x80000000u) atomicAdd(&hist[v.w >> (32 - HBITS)], 1u);
  }
  __syncthreads();
  // ---- P2: threshold bin (proven suffix-scan) ----
  {
    uint32_t c[8], suf[8];
#pragma unroll
    for (int k = 0; k < 8; ++k) c[k] = hist[tid * 8 + k];
    suf[7] = c[7];
#pragma unroll
    for (int k = 6; k >= 0; --k) suf[k] = c[k] + suf[k + 1];
    uint32_t total = suf[0];
    uint32_t wsuf = total;
#pragma unroll
    for (int off = 1; off < 64; off <<= 1) {
      uint32_t v = __shfl_down(wsuf, off);
      if (lane + off < 64) wsuf += v;
    }
    if (lane == 0) wtot[wave] = wsuf;
    __syncthreads();
    uint32_t wab = 0;
    for (int w = wave + 1; w < 16; ++w) wab += wtot[w];
    uint32_t ssum = wsuf + wab;
    uint32_t above_t = ssum - total;
    if (above_t < TOPN && ssum >= TOPN) {
      uint32_t T = (uint32_t)(tid * 8);
#pragma unroll
      for (int k = 7; k >= 0; --k) {
        uint32_t ab = above_t + ((k < 7) ? suf[k + 1] : 0u);
        if (ab < TOPN && ab + c[k] >= TOPN) T = (uint32_t)(tid * 8 + k);
      }
      sh_T = T;
    }
  }
  __syncthreads();
  // ---- P3: compact candidates into LDS ----
  uint32_t T = sh_T;
  for (int i4 = tid; i4 < NANCH / 4; i4 += 1024) {
    uint4 v = kb4[i4];
    uint32_t vv[4] = { v.x, v.y, v.z, v.w };
#pragma unroll
    for (int cc = 0; cc < 4; ++cc) {
      uint32_t u = vv[cc];
      if ((u >> (32 - HBITS)) >= T) {
        uint32_t slot = atomicAdd(&sh_cnt, 1u);
        if (slot < SELPAD) {
          int i = i4 * 4 + cc;
          uint32_t canon = (uint32_t)((i & 4095) * 9 + (i >> 12));  // pos*9 + a
          sel[slot] = (((ull)(~u)) << 32) | canon;
        }
      }
    }
  }
  __syncthreads();
  uint32_t n = sh_cnt; if (n > SELPAD) n = SELPAD;

  // ---- P4: rank-by-counting (3 candidates/thread) + decode + scatter ----
  {
    ull kk0, kk1, kk2;
    int r0 = 0, r1 = 0, r2 = 0;
    kk0 = (tid          < (int)n) ? sel[tid]          : ~0ull;
    kk1 = (tid + 1024   < (int)n) ? sel[tid + 1024]   : ~0ull;
    kk2 = (tid + 2048   < (int)n) ? sel[tid + 2048]   : ~0ull;
    for (uint32_t j = 0; j < n; ++j) {
      ull v = sel[j];
      r0 += (v < kk0); r1 += (v < kk1); r2 += (v < kk2);
    }
    ull kA[3] = { kk0, kk1, kk2 };
    int rA[3] = { r0, r1, r2 };
#pragma unroll
    for (int q = 0; q < 3; ++q) {
      int ci = q * 1024 + tid;
      if (ci < (int)n && rA[q] < TOPN) {
        ull ki = kA[q];
        int rank = rA[q];
        float sc = ord2f(~((uint32_t)(ki >> 32)));
        uint32_t idx = (uint32_t)ki;
        int pos = (int)idx / 9, a = (int)idx - 9 * pos;
        int y = pos >> 6, x = pos & 63;
        const float* dp = bbox + ((b * 36 + 4 * a) << 12) + pos;
        float d0 = dp[0], d1 = dp[4096], d2 = dp[8192], d3 = dp[12288];
        float x1, y1, x2, y2;
        decode_box(a, x, y, d0, d1, d2, d3, x1, y1, x2, y2);
        float ar = (x2 - x1 + 1.f) * (y2 - y1 + 1.f);
        boxes[b * PADN + rank] = make_float4(x1, y1, x2, y2);
        areas[b * PADN + rank] = ar;
        selScore[b * TOPN + rank] = sc;
        if (rank < MNMS) {
          sx1[rank] = x1; sy1[rank] = y1; sx2[rank] = x2; sy2[rank] = y2;
          sar2[rank] = ar;
        }
      }
    }
  }
  __syncthreads();

  const double MD = MIDC;
  // ---- P5: mask build (registers columns, one ballot per 64-bit word) ----
  {
    float cx1[6], cy1[6], cx2[6], cy2[6], ca[6];
#pragma unroll
    for (int s = 0; s < 6; ++s) {
      int j = (s << 6) + lane;
      cx1[s] = sx1[j]; cy1[s] = sy1[j]; cx2[s] = sx2[j]; cy2[s] = sy2[j]; ca[s] = sar2[j];
    }
    for (int i = wave; i < MNMS; i += 16) {
      float ix1 = sx1[i], iy1 = sy1[i], ix2 = sx2[i], iy2 = sy2[i], ia = sar2[i];
      int smin = i >> 6;
#pragma unroll
      for (int s = 0; s < 6; ++s) {
        if (s < smin) continue;              // below-diagonal words stay 0
        int j = (s << 6) + lane;
        float iw = fminf(ix2, cx2[s]) - fmaxf(ix1, cx1[s]) + 1.f; iw = fmaxf(iw, 0.f);
        float ih = fminf(iy2, cy2[s]) - fmaxf(iy1, cy1[s]) + 1.f; ih = fmaxf(ih, 0.f);
        float inter = iw * ih;
        float uu = (ia + ca[s]) - inter;
        bool sup = (j > i) && ((double)inter >= MD * (double)uu);
        ull mb = __ballot(sup);
        if (lane == 0) mrow[i][s] = mb;
      }
    }
  }
  __syncthreads();

  // ---- P6/P7: branchless replicated-bitmap greedy scan + enumeration (wave 0) ----
  if (tid < 64) {
    ull sup0 = 0, sup1 = 0, sup2 = 0, sup3 = 0, sup4 = 0, sup5 = 0;
    ull km0 = 0, km1 = 0, km2 = 0, km3 = 0, km4 = 0, km5 = 0;
    int tot = 0;
    bool fin = false;

#define PR(W0, W1, W2, BITOFF, SUPC, KMC)                                   \
    {                                                                        \
      ull t = (SUPC >> (BITOFF)) & 1ull;                                     \
      KMC |= (t ^ 1ull) << (BITOFF);                                         \
      ull m = t - 1ull;                                                      \
      sup0 |= (W0).x & m; sup1 |= (W0).y & m;                                \
      sup2 |= (W1).x & m; sup3 |= (W1).y & m;                                \
      sup4 |= (W2).x & m; sup5 |= (W2).y & m;                                \
    }

#define DO_CHUNK(C, SUPC, KMC)                                               \
    if (!fin) {                                                              \
      _Pragma("clang loop unroll(disable)")                                  \
      for (int g = 0; g < 16; ++g) {                                         \
        int i0 = ((C) << 6) + (g << 2);                                      \
        const ulonglong2* rpa = (const ulonglong2*)mrow[i0];                 \
        const ulonglong2* rpb = (const ulonglong2*)mrow[i0 + 1];             \
        const ulonglong2* rpc = (const ulonglong2*)mrow[i0 + 2];             \
        const ulonglong2* rpd = (const ulonglong2*)mrow[i0 + 3];             \
        ulonglong2 a0 = rpa[0], a1 = rpa[1], a2 = rpa[2];                    \
        ulonglong2 b0 = rpb[0], b1 = rpb[1], b2 = rpb[2];                    \
        ulonglong2 c0 = rpc[0], c1 = rpc[1], c2 = rpc[2];                    \
        ulonglong2 d0 = rpd[0], d1 = rpd[1], d2 = rpd[2];                    \
        int bo = g << 2;                                                     \
        PR(a0, a1, a2, bo,     SUPC, KMC);                                   \
        PR(b0, b1, b2, bo + 1, SUPC, KMC);                                   \
        PR(c0, c1, c2, bo + 2, SUPC, KMC);                                   \
        PR(d0, d1, d2, bo + 3, SUPC, KMC);                                   \
      }                                                                      \
      tot += (int)__popcll(KMC);                                             \
      if (tot >= OUTN) fin = true;                                           \
    }

    DO_CHUNK(0, sup0, km0);
    DO_CHUNK(1, sup1, km1);
    DO_CHUNK(2, sup2, km2);
    DO_CHUNK(3, sup3, km3);
    DO_CHUNK(4, sup4, km4);
    DO_CHUNK(5, sup5, km5);
#undef DO_CHUNK
#undef PR

    // enumerate kept (index order == greedy order), cap 300
    int cnt = 0;
#define ENUM(KMC, C)                                                         \
    {                                                                        \
      ull w = KMC;                                                           \
      while (w && cnt < OUTN) {                                              \
        int k2 = (int)__builtin_ctzll(w);                                    \
        w &= w - 1ull;                                                       \
        if (lane == 0) kidx[cnt] = ((C) << 6) + k2;                          \
        cnt++;                                                               \
      }                                                                      \
    }
    ENUM(km0, 0); ENUM(km1, 1); ENUM(km2, 2);
    ENUM(km3, 3); ENUM(km4, 4); ENUM(km5, 5);
#undef ENUM

    // exact fallback: candidates beyond MNMS (rare/never)
    if (cnt < OUTN) {
      for (int i = MNMS; i < (int)n && i < TOPN && cnt < OUTN; ++i) {
        float4 bi = boxes[b * PADN + i];
        float ia = areas[b * PADN + i];
        bool sup = false;
        for (int cb2 = 0; cb2 < cnt; cb2 += 64) {
          int k = cb2 + lane;
          if (k < cnt) {
            int kj = kidx[k];
            float4 bk = boxes[b * PADN + kj];
            float ka = areas[b * PADN + kj];
            float iw = fminf(bi.z, bk.z) - fmaxf(bi.x, bk.x) + 1.f; iw = fmaxf(iw, 0.f);
            float ih = fminf(bi.w, bk.w) - fmaxf(bi.y, bk.y) + 1.f; ih = fmaxf(ih, 0.f);
            float inter = iw * ih;
            float uu = (ia + ka) - inter;
            sup = sup || ((double)inter >= MD * (double)uu);
          }
        }
        if (!__any(sup)) {
          if (lane == 0) kidx[cnt] = i;
          cnt++;
        }
      }
    }
    if (lane == 0) sh_c = (cnt < OUTN) ? cnt : OUTN;
  }
  __syncthreads();

  // ---- P8: output ----
  int c2 = sh_c;
  float4* ob = (float4*)out;
  for (int s2 = tid; s2 < OUTN; s2 += 1024) {
    float4 bx = make_float4(0.f, 0.f, 0.f, 0.f);
    float sc = 0.f;
    if (s2 < c2) {
      int i = kidx[s2];
      bx = boxes[b * PADN + i];
      sc = selScore[b * TOPN + i];
    }
    ob[b * OUTN + s2] = bx;
    out[NB * OUTN * 4 + b * OUTN + s2] = sc;
  }
}

extern "C" void kernel_launch(void* const* d_in, const int* in_sizes, int n_in,
                              void* d_out, int out_size, void* d_ws, size_t ws_size,
                              hipStream_t stream) {
  const float* labels = (const float*)d_in[0];  // (16, 18, 64, 64)
  const float* bbox   = (const float*)d_in[1];  // (16, 36, 64, 64)
  char* ws = (char*)d_ws;
  // workspace layout (bytes):
  uint32_t* keys  = (uint32_t*)(ws + 0);        // 589824*4   = 2,359,296
  float4* boxes   = (float4*)(ws + 2359296);    // 16*2048*16 =   524,288
  float* areas    = (float*)(ws + 2883584);     // 16*2048*4  =   131,072
  float* selScore = (float*)(ws + 3014656);     // 16*2000*4  =   128,000
  float* out = (float*)d_out;

  hipLaunchKernelGGL(k_score, dim3(TOTAL / 4 / 256), dim3(256), 0, stream, labels, bbox, keys);
  hipLaunchKernelGGL(k_fused, dim3(NB), dim3(1024), 0, stream, keys, bbox,
                     boxes, areas, selScore, out);
}

// Round 18
// 107.211 us; speedup vs baseline: 1.7032x; 1.7032x over previous
//
#include <hip/hip_runtime.h>
#include <stdint.h>

// Match numpy's unfused mul/add rounding everywhere (no FMA contraction).
#pragma clang fp contract(off)

typedef unsigned long long ull;

// Problem constants (B=16, H=W=64, A=9, stride 16, img 1024x1024)
#define NB 16
#define NA 9
#define HW 4096
#define NANCH (NA*HW)         // 36864
#define TOTAL (NB*NANCH)      // 589824
#define TOPN 2000
#define PADN 2048             // box/area buffer stride
#define SELPAD 3072           // candidate buffer per batch
#define OUTN 300
#define HBITS 13
#define HBINS (1 << HBITS)    // 8192 LDS histogram bins
#define MNMS 384              // mask extent (scan ends ~310; exact fallback past it)
#define MSTRIPS (MNMS/64)     // 6 ull words per row
#define MPITCH 8              // row pitch in ull words (64B-aligned rows)

// exact: RN32(inter/u) > 0.7f  <=>  (double)inter >= MIDC*(double)u
// (HW-verified: absmax 0 in rounds 9-17.)
#define MIDC 0x1.666667p-1

// 9 base anchors (x1,y1,x2,y2), computed exactly per the numpy generator
__constant__ float c_ax1[9] = {-3.5f,-15.f,-38.f,  0.f, -8.f,-24.f,  2.5f, -3.f,-14.f};
__constant__ float c_ay1[9] = { 2.f,  -4.f,-16.f,  0.f, -8.f,-24.f, -3.f,-14.f,-36.f};
__constant__ float c_ax2[9] = {18.5f, 30.f, 53.f, 15.f, 23.f, 39.f, 12.5f, 18.f, 29.f};
__constant__ float c_ay2[9] = {13.f,  19.f, 31.f, 15.f, 23.f, 39.f, 18.f,  29.f, 51.f};

__device__ __forceinline__ void decode_box(int a, int x, int y,
    float d0, float d1, float d2, float d3,
    float& x1, float& y1, float& x2, float& y2) {
  float ax1 = c_ax1[a] + 16.f * (float)x;
  float ay1 = c_ay1[a] + 16.f * (float)y;
  float ax2 = c_ax2[a] + 16.f * (float)x;
  float ay2 = c_ay2[a] + 16.f * (float)y;
  float aw  = ax2 - ax1 + 1.f;
  float ah  = ay2 - ay1 + 1.f;
  float acx = ax1 + 0.5f * aw;
  float acy = ay1 + 0.5f * ah;
  float cx = d0 * aw + acx;
  float cy = d1 * ah + acy;
  float pw = expf(d2) * aw;
  float ph = expf(d3) * ah;
  x1 = cx - 0.5f * pw;
  y1 = cy - 0.5f * ph;
  x2 = cx + 0.5f * pw;
  y2 = cy + 0.5f * ph;
  x1 = fminf(fmaxf(x1, 0.f), 1023.f);
  y1 = fminf(fmaxf(y1, 0.f), 1023.f);
  x2 = fminf(fmaxf(x2, 0.f), 1023.f);
  y2 = fminf(fmaxf(y2, 0.f), 1023.f);
}

__device__ __forceinline__ uint32_t f2ord(float f) {
  uint32_t u = __float_as_uint(f);
  return (u & 0x80000000u) ? ~u : (u | 0x80000000u);
}
__device__ __forceinline__ float ord2f(uint32_t u) {
  return (u & 0x80000000u) ? __uint_as_float(u ^ 0x80000000u) : __uint_as_float(~u);
}

// Kernel 1: masked ordered score keys, 4 anchors/thread (float4 loads, uint4
// store, [b][a][pos] layout). Proven rounds 16-17.
__global__ void k_score(const float* __restrict__ labels, const float* __restrict__ bbox,
                        uint32_t* __restrict__ keys) {
  int t4 = blockIdx.x * 256 + threadIdx.x;     // grid 576 -> t4 < TOTAL/4
  int p4 = t4 & 1023;                          // float4 index within (b,a) plane
  int pos = p4 << 2;
  int ba = t4 >> 10;                           // b*9 + a  (0..143)
  int a = ba % 9, b = ba / 9;
  float4 sc  = ((const float4*)(labels + ((b * 18 + 2 * a + 1) << 12)))[p4];
  const float* dpb = bbox + ((b * 36 + 4 * a) << 12);
  float4 d0v = ((const float4*)(dpb        ))[p4];
  float4 d1v = ((const float4*)(dpb +  4096))[p4];
  float4 d2v = ((const float4*)(dpb +  8192))[p4];
  float4 d3v = ((const float4*)(dpb + 12288))[p4];
  int y = pos >> 6, x0 = pos & 63;             // pos%4==0 -> never crosses row
  float scA[4] = { sc.x,  sc.y,  sc.z,  sc.w  };
  float d0A[4] = { d0v.x, d0v.y, d0v.z, d0v.w };
  float d1A[4] = { d1v.x, d1v.y, d1v.z, d1v.w };
  float d2A[4] = { d2v.x, d2v.y, d2v.z, d2v.w };
  float d3A[4] = { d3v.x, d3v.y, d3v.z, d3v.w };
  uint32_t kout[4];
#pragma unroll
  for (int k = 0; k < 4; ++k) {
    float x1, y1, x2, y2;
    decode_box(a, x0 + k, y, d0A[k], d1A[k], d2A[k], d3A[k], x1, y1, x2, y2);
    bool keep = (x2 - x1 + 1.f >= 16.f) && (y2 - y1 + 1.f >= 16.f);
    kout[k] = f2ord(keep ? scA[k] : -INFINITY);
  }
  ((uint4*)(keys + b * NANCH + (a << 12) + pos))[0] =
      make_uint4(kout[0], kout[1], kout[2], kout[3]);
}

// Kernel 2: per-batch LDS histogram + suffix scan for top-2000 threshold bin
// + compaction. 16 blocks x 1024. Proven round 15.
__global__ __launch_bounds__(1024) void k_batch(const uint32_t* __restrict__ keys,
                                                ull* __restrict__ selKeys,
                                                uint32_t* __restrict__ counters) {
  int b = blockIdx.x, tid = threadIdx.x;
  int wave = tid >> 6, lane = tid & 63;
  __shared__ uint32_t hist[HBINS];         // 32 KB
  __shared__ uint32_t wtot[16];
  __shared__ uint32_t sh_T, sh_cnt;
  const uint32_t* kb = keys + b * NANCH;
  const uint4* kb4 = (const uint4*)kb;
#pragma unroll
  for (int k = 0; k < HBINS / 1024; ++k) hist[k * 1024 + tid] = 0u;
  if (tid == 0) { sh_T = 0u; sh_cnt = 0u; }
  __syncthreads();
  for (int i4 = tid; i4 < NANCH / 4; i4 += 1024) {
    uint4 v = kb4[i4];
    if (v.x & 0x80000000u) atomicAdd(&hist[v.x >> (32 - HBITS)], 1u);
    if (v.y & 0x80000000u) atomicAdd(&hist[v.y >> (32 - HBITS)], 1u);
    if (v.z & 0x80000000u) atomicAdd(&hist[v.z >> (32 - HBITS)], 1u);
    if (v.w & 0x80000000u) atomicAdd(&hist[v.w >> (32 - HBITS)], 1u);
  }
  __syncthreads();
  uint32_t c[8], suf[8];
#pragma unroll
  for (int k = 0; k < 8; ++k) c[k] = hist[tid * 8 + k];
  suf[7] = c[7];
#pragma unroll
  for (int k = 6; k >= 0; --k) suf[k] = c[k] + suf[k + 1];
  uint32_t total = suf[0];
  uint32_t wsuf = total;
#pragma unroll
  for (int off = 1; off < 64; off <<= 1) {
    uint32_t v = __shfl_down(wsuf, off);
    if (lane + off < 64) wsuf += v;
  }
  if (lane == 0) wtot[wave] = wsuf;
  __syncthreads();
  uint32_t wab = 0;
  for (int w = wave + 1; w < 16; ++w) wab += wtot[w];
  uint32_t ssum = wsuf + wab;          // keys in bins >= 8*tid
  uint32_t above_t = ssum - total;     // keys in bins >= 8*(tid+1)
  if (above_t < TOPN && ssum >= TOPN) {
    uint32_t T = (uint32_t)(tid * 8);
#pragma unroll
    for (int k = 7; k >= 0; --k) {
      uint32_t ab = above_t + ((k < 7) ? suf[k + 1] : 0u);
      if (ab < TOPN && ab + c[k] >= TOPN) T = (uint32_t)(tid * 8 + k);
    }
    sh_T = T;
  }
  __syncthreads();
  uint32_t T = sh_T;
  for (int i4 = tid; i4 < NANCH / 4; i4 += 1024) {
    uint4 v = kb4[i4];
    uint32_t vv[4] = { v.x, v.y, v.z, v.w };
#pragma unroll
    for (int cc = 0; cc < 4; ++cc) {
      uint32_t u = vv[cc];
      if ((u >> (32 - HBITS)) >= T) {
        uint32_t slot = atomicAdd(&sh_cnt, 1u);
        if (slot < SELPAD) {
          int i = i4 * 4 + cc;
          uint32_t canon = (uint32_t)((i & 4095) * 9 + (i >> 12));  // pos*9 + a
          selKeys[b * SELPAD + slot] = (((ull)(~u)) << 32) | canon;
        }
      }
    }
  }
  __syncthreads();
  if (tid == 0) counters[b] = (sh_cnt < SELPAD) ? sh_cnt : SELPAD;
}

// Kernel 3: rank-by-counting + decode + scatter. Proven round 15.
__global__ __launch_bounds__(256) void k_rank(const ull* __restrict__ selKeys,
                        const uint32_t* __restrict__ counters, const float* __restrict__ bbox,
                        float4* __restrict__ boxes, float* __restrict__ areas,
                        float* __restrict__ selScore) {
  int b = blockIdx.y;
  int i = blockIdx.x * 256 + threadIdx.x;
  int tid = threadIdx.x;
  uint32_t n = counters[b];
  const ull* sk = selKeys + b * SELPAD;
  ull ki = (i < (int)n) ? sk[i] : ~0ull;
  int rank = 0;
  __shared__ ull chunk[256];
  for (uint32_t base = 0; base < n; base += 256) {
    uint32_t j = base + (uint32_t)tid;
    chunk[tid] = (j < n) ? sk[j] : ~0ull;
    __syncthreads();
    int lim = (int)(n - base < 256u ? n - base : 256u);
    for (int t2 = 0; t2 < lim; ++t2) rank += (chunk[t2] < ki) ? 1 : 0;
    __syncthreads();
  }
  if (i < (int)n && rank < TOPN) {
    uint32_t idx = (uint32_t)ki;
    selScore[b * TOPN + rank] = ord2f(~((uint32_t)(ki >> 32)));
    int pos = (int)idx / 9, a = (int)idx - 9 * pos;
    int y = pos >> 6, x = pos & 63;
    const float* dp = bbox + ((b * 36 + 4 * a) << 12) + pos;
    float d0 = dp[0], d1 = dp[4096], d2 = dp[8192], d3 = dp[12288];
    float x1, y1, x2, y2;
    decode_box(a, x, y, d0, d1, d2, d3, x1, y1, x2, y2);
    boxes[b * PADN + rank] = make_float4(x1, y1, x2, y2);
    areas[b * PADN + rank] = (x2 - x1 + 1.f) * (y2 - y1 + 1.f);
  }
}

// Kernel 4: suppression mask build, 192 balanced blocks. Proven round 15.
// Writes words s in [smin, 6) of rows [rbase, rbase+32); k_scan2 zeroes the
// rest at stage time.
__global__ __launch_bounds__(256) void k_mask(const float4* __restrict__ boxes,
                                              const float* __restrict__ areas,
                                              ull* __restrict__ gmask) {
  int rb = blockIdx.x, b = blockIdx.y;
  int tid = threadIdx.x, wv = tid >> 6, lane = tid & 63;
  int rbase = rb * 32;
  int smin = rbase >> 6;
  __shared__ float4 sRow[32];
  __shared__ float  sAr[32];
  if (tid < 32) {
    sRow[tid] = boxes[b * PADN + rbase + tid];
    sAr[tid]  = areas[b * PADN + rbase + tid];
  }
  float4 bj[MSTRIPS];
  float  ja[MSTRIPS];
#pragma unroll
  for (int s = 0; s < MSTRIPS; ++s) {
    if (s >= smin) {
      bj[s] = boxes[b * PADN + (s << 6) + lane];
      ja[s] = areas[b * PADN + (s << 6) + lane];
    }
  }
  __syncthreads();
  const double MD = MIDC;
  for (int r = wv; r < 32; r += 4) {
    int i = rbase + r;
    float4 bi = sRow[r];
    float  ia = sAr[r];
#pragma unroll
    for (int s = 0; s < MSTRIPS; ++s) {
      if (s < smin) continue;
      int j = (s << 6) + lane;
      float iw = fminf(bi.z, bj[s].z) - fmaxf(bi.x, bj[s].x) + 1.f; iw = fmaxf(iw, 0.f);
      float ih = fminf(bi.w, bj[s].w) - fmaxf(bi.y, bj[s].y) + 1.f; ih = fmaxf(ih, 0.f);
      float inter = iw * ih;
      float uu = (ia + ja[s]) - inter;
      bool sup = (j > i) && ((double)inter >= MD * (double)uu);
      ull mb = __ballot(sup);
      if (lane == 0) gmask[((size_t)b * MNMS + i) * MPITCH + s] = mb;
    }
  }
}

// Kernel 5: branchless replicated-bitmap greedy scan. 16 blocks x 256.
// Stage the 24 KB mask matrix into LDS (coalesced; invalid words zeroed),
// then wave 0 scans: all 6 sup/kept words in named registers, per row
// ~3 LDS b128 + 8 VALU ops, no ballot, no branch. Enumeration in index
// order == exact greedy order; exact fallback for candidates >= MNMS.
__global__ __launch_bounds__(256) void k_scan2(const ull* __restrict__ gmask,
                                               const float4* __restrict__ boxes,
                                               const float* __restrict__ areas,
                                               const float* __restrict__ selScore,
                                               float* __restrict__ out) {
  int b = blockIdx.x, tid = threadIdx.x;
  int lane = tid & 63;
  __shared__ ull __attribute__((aligned(16))) lmr[MNMS][MPITCH];  // 24 KB
  __shared__ int kidx[OUTN];
  __shared__ int sh_c;
  const ull* gm = gmask + (size_t)b * MNMS * MPITCH;
  // stage, zeroing below-diagonal / unused words (w < row>>6 or w >= 6)
  for (int k = tid; k < MNMS * MPITCH; k += 256) {
    int row = k >> 3, w = k & 7;
    bool valid = (w >= (row >> 6)) && (w < MSTRIPS);
    ((ull*)lmr)[k] = valid ? gm[k] : 0ull;
  }
  __syncthreads();
  const double MD = MIDC;
  if (tid < 64) {
    ull sup0 = 0, sup1 = 0, sup2 = 0, sup3 = 0, sup4 = 0, sup5 = 0;
    ull km0 = 0, km1 = 0, km2 = 0, km3 = 0, km4 = 0, km5 = 0;
    int tot = 0;
    bool fin = false;

#define PR(W0, W1, W2, BITOFF, SUPC, KMC)                                   \
    {                                                                        \
      ull t = (SUPC >> (BITOFF)) & 1ull;                                     \
      KMC |= (t ^ 1ull) << (BITOFF);                                         \
      ull m = t - 1ull;                                                      \
      sup0 |= (W0).x & m; sup1 |= (W0).y & m;                                \
      sup2 |= (W1).x & m; sup3 |= (W1).y & m;                                \
      sup4 |= (W2).x & m; sup5 |= (W2).y & m;                                \
    }

#define DO_CHUNK(C, SUPC, KMC)                                               \
    if (!fin) {                                                              \
      _Pragma("clang loop unroll(disable)")                                  \
      for (int g = 0; g < 16; ++g) {                                         \
        int i0 = ((C) << 6) + (g << 2);                                      \
        const ulonglong2* rpa = (const ulonglong2*)lmr[i0];                  \
        const ulonglong2* rpb = (const ulonglong2*)lmr[i0 + 1];              \
        const ulonglong2* rpc = (const ulonglong2*)lmr[i0 + 2];              \
        const ulonglong2* rpd = (const ulonglong2*)lmr[i0 + 3];              \
        ulonglong2 a0 = rpa[0], a1 = rpa[1], a2 = rpa[2];                    \
        ulonglong2 b0 = rpb[0], b1 = rpb[1], b2 = rpb[2];                    \
        ulonglong2 c0 = rpc[0], c1 = rpc[1], c2 = rpc[2];                    \
        ulonglong2 d0 = rpd[0], d1 = rpd[1], d2 = rpd[2];                    \
        int bo = g << 2;                                                     \
        PR(a0, a1, a2, bo,     SUPC, KMC);                                   \
        PR(b0, b1, b2, bo + 1, SUPC, KMC);                                   \
        PR(c0, c1, c2, bo + 2, SUPC, KMC);                                   \
        PR(d0, d1, d2, bo + 3, SUPC, KMC);                                   \
      }                                                                      \
      tot += (int)__popcll(KMC);                                             \
      if (tot >= OUTN) fin = true;                                           \
    }

    DO_CHUNK(0, sup0, km0);
    DO_CHUNK(1, sup1, km1);
    DO_CHUNK(2, sup2, km2);
    DO_CHUNK(3, sup3, km3);
    DO_CHUNK(4, sup4, km4);
    DO_CHUNK(5, sup5, km5);
#undef DO_CHUNK
#undef PR

    int cnt = 0;
#define ENUM(KMC, C)                                                         \
    {                                                                        \
      ull w = KMC;                                                           \
      while (w && cnt < OUTN) {                                              \
        int k2 = (int)__builtin_ctzll(w);                                    \
        w &= w - 1ull;                                                       \
        if (lane == 0) kidx[cnt] = ((C) << 6) + k2;                          \
        cnt++;                                                               \
      }                                                                      \
    }
    ENUM(km0, 0); ENUM(km1, 1); ENUM(km2, 2);
    ENUM(km3, 3); ENUM(km4, 4); ENUM(km5, 5);
#undef ENUM

    // exact fallback: candidates beyond the mask matrix (rare/never)
    if (cnt < OUTN) {
      for (int i = MNMS; i < TOPN && cnt < OUTN; ++i) {
        float4 bi = boxes[b * PADN + i];
        float ia = areas[b * PADN + i];
        bool sup = false;
        for (int cb2 = 0; cb2 < cnt; cb2 += 64) {
          int k = cb2 + lane;
          if (k < cnt) {
            int kj = kidx[k];
            float4 bk = boxes[b * PADN + kj];
            float ka = areas[b * PADN + kj];
            float iw = fminf(bi.z, bk.z) - fmaxf(bi.x, bk.x) + 1.f; iw = fmaxf(iw, 0.f);
            float ih = fminf(bi.w, bk.w) - fmaxf(bi.y, bk.y) + 1.f; ih = fmaxf(ih, 0.f);
            float inter = iw * ih;
            float uu = (ia + ka) - inter;
            sup = sup || ((double)inter >= MD * (double)uu);
          }
        }
        if (!__any(sup)) {
          if (lane == 0) kidx[cnt] = i;
          cnt++;
        }
      }
    }
    if (lane == 0) sh_c = (cnt < OUTN) ? cnt : OUTN;
  }
  __syncthreads();
  int c2 = sh_c;
  float4* ob = (float4*)out;
  for (int s2 = tid; s2 < OUTN; s2 += 256) {
    float4 bx = make_float4(0.f, 0.f, 0.f, 0.f);
    float sc = 0.f;
    if (s2 < c2) {
      int i = kidx[s2];
      bx = boxes[b * PADN + i];
      sc = selScore[b * TOPN + i];
    }
    ob[b * OUTN + s2] = bx;
    out[NB * OUTN * 4 + b * OUTN + s2] = sc;
  }
}

extern "C" void kernel_launch(void* const* d_in, const int* in_sizes, int n_in,
                              void* d_out, int out_size, void* d_ws, size_t ws_size,
                              hipStream_t stream) {
  const float* labels = (const float*)d_in[0];  // (16, 18, 64, 64)
  const float* bbox   = (const float*)d_in[1];  // (16, 36, 64, 64)
  char* ws = (char*)d_ws;
  // workspace layout (bytes):
  uint32_t* keys    = (uint32_t*)(ws + 0);         // 589824*4    = 2,359,296
  ull* selKeys      = (ull*)(ws + 2359296);        // 16*3072*8   =   393,216
  float* selScore   = (float*)(ws + 2752512);      // 16*2000*4   =   128,000
  float* areas      = (float*)(ws + 2880512);      // 16*2048*4   =   131,072
  float4* boxes     = (float4*)(ws + 3011584);     // 16*2048*16  =   524,288
  uint32_t* counters= (uint32_t*)(ws + 3535872);   // 64
  ull* gmask        = (ull*)(ws + 3535936);        // 16*384*8*8  =   393,216
  float* out = (float*)d_out;

  hipLaunchKernelGGL(k_score, dim3(TOTAL / 4 / 256), dim3(256), 0, stream, labels, bbox, keys);
  hipLaunchKernelGGL(k_batch, dim3(NB), dim3(1024), 0, stream, keys, selKeys, counters);
  hipLaunchKernelGGL(k_rank,  dim3(SELPAD / 256, NB), dim3(256), 0, stream, selKeys, counters, bbox, boxes, areas, selScore);
  hipLaunchKernelGGL(k_mask,  dim3(MNMS / 32, NB), dim3(256), 0, stream, boxes, areas, gmask);
  hipLaunchKernelGGL(k_scan2, dim3(NB), dim3(256), 0, stream, gmask, boxes, areas, selScore, out);
}

// Round 19
// 97.858 us; speedup vs baseline: 1.8660x; 1.0956x over previous
//
#include <hip/hip_runtime.h>
#include <stdint.h>

// Match numpy's unfused mul/add rounding everywhere (no FMA contraction).
#pragma clang fp contract(off)

typedef unsigned long long ull;

// Problem constants (B=16, H=W=64, A=9, stride 16, img 1024x1024)
#define NB 16
#define NA 9
#define HW 4096
#define NANCH (NA*HW)         // 36864
#define TOTAL (NB*NANCH)      // 589824
#define TOPN 2000
#define PADN 2048             // box/area buffer stride
#define SELPAD 3072           // candidate buffer per batch
#define OUTN 300
#define HBITS 13
#define HBINS (1 << HBITS)    // 8192 LDS histogram bins
#define MNMS 768              // mask extent (300 kept reached ~(384,512]; margin)
#define MSTRIPS (MNMS/64)     // 12 ull words per row
#define MPITCH 16             // row pitch in ull words (128B-aligned rows)
#define GD2 16                // scan prefetch depth

// exact: RN32(inter/u) > 0.7f  <=>  (double)inter >= MIDC*(double)u
// (HW-verified: absmax 0 in rounds 9-18.)
#define MIDC 0x1.666667p-1

// 9 base anchors (x1,y1,x2,y2), computed exactly per the numpy generator
__constant__ float c_ax1[9] = {-3.5f,-15.f,-38.f,  0.f, -8.f,-24.f,  2.5f, -3.f,-14.f};
__constant__ float c_ay1[9] = { 2.f,  -4.f,-16.f,  0.f, -8.f,-24.f, -3.f,-14.f,-36.f};
__constant__ float c_ax2[9] = {18.5f, 30.f, 53.f, 15.f, 23.f, 39.f, 12.5f, 18.f, 29.f};
__constant__ float c_ay2[9] = {13.f,  19.f, 31.f, 15.f, 23.f, 39.f, 18.f,  29.f, 51.f};

__device__ __forceinline__ void decode_box(int a, int x, int y,
    float d0, float d1, float d2, float d3,
    float& x1, float& y1, float& x2, float& y2) {
  float ax1 = c_ax1[a] + 16.f * (float)x;
  float ay1 = c_ay1[a] + 16.f * (float)y;
  float ax2 = c_ax2[a] + 16.f * (float)x;
  float ay2 = c_ay2[a] + 16.f * (float)y;
  float aw  = ax2 - ax1 + 1.f;
  float ah  = ay2 - ay1 + 1.f;
  float acx = ax1 + 0.5f * aw;
  float acy = ay1 + 0.5f * ah;
  float cx = d0 * aw + acx;
  float cy = d1 * ah + acy;
  float pw = expf(d2) * aw;
  float ph = expf(d3) * ah;
  x1 = cx - 0.5f * pw;
  y1 = cy - 0.5f * ph;
  x2 = cx + 0.5f * pw;
  y2 = cy + 0.5f * ph;
  x1 = fminf(fmaxf(x1, 0.f), 1023.f);
  y1 = fminf(fmaxf(y1, 0.f), 1023.f);
  x2 = fminf(fmaxf(x2, 0.f), 1023.f);
  y2 = fminf(fmaxf(y2, 0.f), 1023.f);
}

__device__ __forceinline__ uint32_t f2ord(float f) {
  uint32_t u = __float_as_uint(f);
  return (u & 0x80000000u) ? ~u : (u | 0x80000000u);
}
__device__ __forceinline__ float ord2f(uint32_t u) {
  return (u & 0x80000000u) ? __uint_as_float(u ^ 0x80000000u) : __uint_as_float(~u);
}

// Kernel 1: masked ordered score keys, 4 anchors/thread. Proven rounds 16-18.
__global__ void k_score(const float* __restrict__ labels, const float* __restrict__ bbox,
                        uint32_t* __restrict__ keys) {
  int t4 = blockIdx.x * 256 + threadIdx.x;     // grid 576 -> t4 < TOTAL/4
  int p4 = t4 & 1023;                          // float4 index within (b,a) plane
  int pos = p4 << 2;
  int ba = t4 >> 10;                           // b*9 + a  (0..143)
  int a = ba % 9, b = ba / 9;
  float4 sc  = ((const float4*)(labels + ((b * 18 + 2 * a + 1) << 12)))[p4];
  const float* dpb = bbox + ((b * 36 + 4 * a) << 12);
  float4 d0v = ((const float4*)(dpb        ))[p4];
  float4 d1v = ((const float4*)(dpb +  4096))[p4];
  float4 d2v = ((const float4*)(dpb +  8192))[p4];
  float4 d3v = ((const float4*)(dpb + 12288))[p4];
  int y = pos >> 6, x0 = pos & 63;             // pos%4==0 -> never crosses row
  float scA[4] = { sc.x,  sc.y,  sc.z,  sc.w  };
  float d0A[4] = { d0v.x, d0v.y, d0v.z, d0v.w };
  float d1A[4] = { d1v.x, d1v.y, d1v.z, d1v.w };
  float d2A[4] = { d2v.x, d2v.y, d2v.z, d2v.w };
  float d3A[4] = { d3v.x, d3v.y, d3v.z, d3v.w };
  uint32_t kout[4];
#pragma unroll
  for (int k = 0; k < 4; ++k) {
    float x1, y1, x2, y2;
    decode_box(a, x0 + k, y, d0A[k], d1A[k], d2A[k], d3A[k], x1, y1, x2, y2);
    bool keep = (x2 - x1 + 1.f >= 16.f) && (y2 - y1 + 1.f >= 16.f);
    kout[k] = f2ord(keep ? scA[k] : -INFINITY);
  }
  ((uint4*)(keys + b * NANCH + (a << 12) + pos))[0] =
      make_uint4(kout[0], kout[1], kout[2], kout[3]);
}

// Kernel 2: per-batch LDS histogram + suffix scan for top-2000 threshold bin
// + compaction. 16 blocks x 1024. Proven round 15.
__global__ __launch_bounds__(1024) void k_batch(const uint32_t* __restrict__ keys,
                                                ull* __restrict__ selKeys,
                                                uint32_t* __restrict__ counters) {
  int b = blockIdx.x, tid = threadIdx.x;
  int wave = tid >> 6, lane = tid & 63;
  __shared__ uint32_t hist[HBINS];         // 32 KB
  __shared__ uint32_t wtot[16];
  __shared__ uint32_t sh_T, sh_cnt;
  const uint32_t* kb = keys + b * NANCH;
  const uint4* kb4 = (const uint4*)kb;
#pragma unroll
  for (int k = 0; k < HBINS / 1024; ++k) hist[k * 1024 + tid] = 0u;
  if (tid == 0) { sh_T = 0u; sh_cnt = 0u; }
  __syncthreads();
  for (int i4 = tid; i4 < NANCH / 4; i4 += 1024) {
    uint4 v = kb4[i4];
    if (v.x & 0x80000000u) atomicAdd(&hist[v.x >> (32 - HBITS)], 1u);
    if (v.y & 0x80000000u) atomicAdd(&hist[v.y >> (32 - HBITS)], 1u);
    if (v.z & 0x80000000u) atomicAdd(&hist[v.z >> (32 - HBITS)], 1u);
    if (v.w & 0x80000000u) atomicAdd(&hist[v.w >> (32 - HBITS)], 1u);
  }
  __syncthreads();
  uint32_t c[8], suf[8];
#pragma unroll
  for (int k = 0; k < 8; ++k) c[k] = hist[tid * 8 + k];
  suf[7] = c[7];
#pragma unroll
  for (int k = 6; k >= 0; --k) suf[k] = c[k] + suf[k + 1];
  uint32_t total = suf[0];
  uint32_t wsuf = total;
#pragma unroll
  for (int off = 1; off < 64; off <<= 1) {
    uint32_t v = __shfl_down(wsuf, off);
    if (lane + off < 64) wsuf += v;
  }
  if (lane == 0) wtot[wave] = wsuf;
  __syncthreads();
  uint32_t wab = 0;
  for (int w = wave + 1; w < 16; ++w) wab += wtot[w];
  uint32_t ssum = wsuf + wab;          // keys in bins >= 8*tid
  uint32_t above_t = ssum - total;     // keys in bins >= 8*(tid+1)
  if (above_t < TOPN && ssum >= TOPN) {
    uint32_t T = (uint32_t)(tid * 8);
#pragma unroll
    for (int k = 7; k >= 0; --k) {
      uint32_t ab = above_t + ((k < 7) ? suf[k + 1] : 0u);
      if (ab < TOPN && ab + c[k] >= TOPN) T = (uint32_t)(tid * 8 + k);
    }
    sh_T = T;
  }
  __syncthreads();
  uint32_t T = sh_T;
  for (int i4 = tid; i4 < NANCH / 4; i4 += 1024) {
    uint4 v = kb4[i4];
    uint32_t vv[4] = { v.x, v.y, v.z, v.w };
#pragma unroll
    for (int cc = 0; cc < 4; ++cc) {
      uint32_t u = vv[cc];
      if ((u >> (32 - HBITS)) >= T) {
        uint32_t slot = atomicAdd(&sh_cnt, 1u);
        if (slot < SELPAD) {
          int i = i4 * 4 + cc;
          uint32_t canon = (uint32_t)((i & 4095) * 9 + (i >> 12));  // pos*9 + a
          selKeys[b * SELPAD + slot] = (((ull)(~u)) << 32) | canon;
        }
      }
    }
  }
  __syncthreads();
  if (tid == 0) counters[b] = (sh_cnt < SELPAD) ? sh_cnt : SELPAD;
}

// Kernel 3: rank-by-counting + decode + scatter. Proven round 15.
__global__ __launch_bounds__(256) void k_rank(const ull* __restrict__ selKeys,
                        const uint32_t* __restrict__ counters, const float* __restrict__ bbox,
                        float4* __restrict__ boxes, float* __restrict__ areas,
                        float* __restrict__ selScore) {
  int b = blockIdx.y;
  int i = blockIdx.x * 256 + threadIdx.x;
  int tid = threadIdx.x;
  uint32_t n = counters[b];
  const ull* sk = selKeys + b * SELPAD;
  ull ki = (i < (int)n) ? sk[i] : ~0ull;
  int rank = 0;
  __shared__ ull chunk[256];
  for (uint32_t base = 0; base < n; base += 256) {
    uint32_t j = base + (uint32_t)tid;
    chunk[tid] = (j < n) ? sk[j] : ~0ull;
    __syncthreads();
    int lim = (int)(n - base < 256u ? n - base : 256u);
    for (int t2 = 0; t2 < lim; ++t2) rank += (chunk[t2] < ki) ? 1 : 0;
    __syncthreads();
  }
  if (i < (int)n && rank < TOPN) {
    uint32_t idx = (uint32_t)ki;
    selScore[b * TOPN + rank] = ord2f(~((uint32_t)(ki >> 32)));
    int pos = (int)idx / 9, a = (int)idx - 9 * pos;
    int y = pos >> 6, x = pos & 63;
    const float* dp = bbox + ((b * 36 + 4 * a) << 12) + pos;
    float d0 = dp[0], d1 = dp[4096], d2 = dp[8192], d3 = dp[12288];
    float x1, y1, x2, y2;
    decode_box(a, x, y, d0, d1, d2, d3, x1, y1, x2, y2);
    boxes[b * PADN + rank] = make_float4(x1, y1, x2, y2);
    areas[b * PADN + rank] = (x2 - x1 + 1.f) * (y2 - y1 + 1.f);
  }
}

// Kernel 4: suppression mask build, 384 balanced blocks: grid (24, 16) x 256.
// Block owns 32 consecutive rows (shares smin = rbase>>6) and writes words
// s in [smin, 12). Lane owns column (s<<6)+lane (box in registers); one
// __ballot builds each 64-bit word. Structure proven round 15 (6 strips).
__global__ __launch_bounds__(256) void k_mask(const float4* __restrict__ boxes,
                                              const float* __restrict__ areas,
                                              ull* __restrict__ gmask) {
  int rb = blockIdx.x, b = blockIdx.y;
  int tid = threadIdx.x, wv = tid >> 6, lane = tid & 63;
  int rbase = rb * 32;
  int smin = rbase >> 6;
  __shared__ float4 sRow[32];
  __shared__ float  sAr[32];
  if (tid < 32) {
    sRow[tid] = boxes[b * PADN + rbase + tid];
    sAr[tid]  = areas[b * PADN + rbase + tid];
  }
  float4 bj[MSTRIPS];
  float  ja[MSTRIPS];
#pragma unroll
  for (int s = 0; s < MSTRIPS; ++s) {
    if (s >= smin) {
      bj[s] = boxes[b * PADN + (s << 6) + lane];
      ja[s] = areas[b * PADN + (s << 6) + lane];
    }
  }
  __syncthreads();
  const double MD = MIDC;
  for (int r = wv; r < 32; r += 4) {
    int i = rbase + r;
    float4 bi = sRow[r];
    float  ia = sAr[r];
#pragma unroll
    for (int s = 0; s < MSTRIPS; ++s) {
      if (s < smin) continue;
      int j = (s << 6) + lane;
      float iw = fminf(bi.z, bj[s].z) - fmaxf(bi.x, bj[s].x) + 1.f; iw = fmaxf(iw, 0.f);
      float ih = fminf(bi.w, bj[s].w) - fmaxf(bi.y, bj[s].y) + 1.f; ih = fmaxf(ih, 0.f);
      float inter = iw * ih;
      float uu = (ia + ja[s]) - inter;
      bool sup = (j > i) && ((double)inter >= MD * (double)uu);
      ull mb = __ballot(sup);
      if (lane == 0) gmask[((size_t)b * MNMS + i) * MPITCH + s] = mb;
    }
  }
}

// Kernel 5: single-wave greedy scan per batch over the global mask matrix,
// GD2-deep register prefetch, ballot bit test, exact early exit at 300 kept.
// Lane (lane&15) owns word (lane&15); words < i>>6 or >= 12 masked invalid.
// Exact fallback for candidates >= MNMS (now provably unreachable: 300 kept
// is reached by ~(384,512] << 768). Structure proven round 15.
__global__ __launch_bounds__(64) void k_scan(const ull* __restrict__ gmask,
                                             const float4* __restrict__ boxes,
                                             const float* __restrict__ areas,
                                             const float* __restrict__ selScore,
                                             float* __restrict__ out) {
  int b = blockIdx.x, lane = threadIdx.x;   // 64 threads = 1 wave
  const ull* mb = gmask + (size_t)b * MNMS * MPITCH;
  int l16 = lane & 15;
  __shared__ int kidx[OUTN];
  __shared__ int sh_cnt;
  const double MD = MIDC;
  ull supw = 0ull;
  int cnt = 0;
  ull pf[GD2];
#pragma unroll
  for (int ph = 0; ph < GD2; ++ph) pf[ph] = mb[ph * MPITCH + l16];
  for (int base = 0; base < MNMS && cnt < OUTN; base += GD2) {
#pragma unroll
    for (int ph = 0; ph < GD2; ++ph) {
      int i = base + ph;
      ull bal = __ballot(((supw >> (i & 63)) & 1ull) != 0ull);
      if (!((bal >> (i >> 6)) & 1ull)) {       // uniform (lane i>>6 owns word)
        ull mm = (l16 >= (i >> 6) && l16 < MSTRIPS) ? pf[ph] : 0ull;
        supw |= mm;
        if (lane == 0 && cnt < OUTN) kidx[cnt] = i;
        cnt++;
      }
      int nx = i + GD2; if (nx > MNMS - 1) nx = MNMS - 1;
      pf[ph] = mb[nx * MPITCH + l16];          // prefetch
    }
  }
  // exact fallback: candidates beyond the mask matrix (unreachable safety net)
  for (int i = MNMS; i < TOPN && cnt < OUTN; ++i) {
    float4 bi = boxes[b * PADN + i];
    float ia = areas[b * PADN + i];
    bool sup = false;
    for (int cb = 0; cb < cnt; cb += 64) {
      int k = cb + lane;
      if (k < cnt) {
        int kj = kidx[k];
        float4 bk = boxes[b * PADN + kj];
        float ka = areas[b * PADN + kj];
        float iw = fminf(bi.z, bk.z) - fmaxf(bi.x, bk.x) + 1.f; iw = fmaxf(iw, 0.f);
        float ih = fminf(bi.w, bk.w) - fmaxf(bi.y, bk.y) + 1.f; ih = fmaxf(ih, 0.f);
        float inter = iw * ih;
        float uu = (ia + ka) - inter;
        sup = sup || ((double)inter >= MD * (double)uu);
      }
    }
    if (!__any(sup)) {
      if (lane == 0) kidx[cnt] = i;
      cnt++;
    }
  }
  if (lane == 0) sh_cnt = (cnt < OUTN) ? cnt : OUTN;
  __syncthreads();
  int c = sh_cnt;
  float4* ob = (float4*)out;
  for (int s2 = lane; s2 < OUTN; s2 += 64) {
    float4 bx = make_float4(0.f, 0.f, 0.f, 0.f);
    float sc = 0.f;
    if (s2 < c) {
      int i = kidx[s2];
      bx = boxes[b * PADN + i];
      sc = selScore[b * TOPN + i];
    }
    ob[b * OUTN + s2] = bx;
    out[NB * OUTN * 4 + b * OUTN + s2] = sc;
  }
}

extern "C" void kernel_launch(void* const* d_in, const int* in_sizes, int n_in,
                              void* d_out, int out_size, void* d_ws, size_t ws_size,
                              hipStream_t stream) {
  const float* labels = (const float*)d_in[0];  // (16, 18, 64, 64)
  const float* bbox   = (const float*)d_in[1];  // (16, 36, 64, 64)
  char* ws = (char*)d_ws;
  // workspace layout (bytes):
  uint32_t* keys    = (uint32_t*)(ws + 0);         // 589824*4     = 2,359,296
  ull* selKeys      = (ull*)(ws + 2359296);        // 16*3072*8    =   393,216
  float* selScore   = (float*)(ws + 2752512);      // 16*2000*4    =   128,000
  float* areas      = (float*)(ws + 2880512);      // 16*2048*4    =   131,072
  float4* boxes     = (float4*)(ws + 3011584);     // 16*2048*16   =   524,288
  uint32_t* counters= (uint32_t*)(ws + 3535872);   // 64
  ull* gmask        = (ull*)(ws + 3535936);        // 16*768*16*8  = 1,572,864
  float* out = (float*)d_out;

  hipLaunchKernelGGL(k_score, dim3(TOTAL / 4 / 256), dim3(256), 0, stream, labels, bbox, keys);
  hipLaunchKernelGGL(k_batch, dim3(NB), dim3(1024), 0, stream, keys, selKeys, counters);
  hipLaunchKernelGGL(k_rank,  dim3(SELPAD / 256, NB), dim3(256), 0, stream, selKeys, counters, bbox, boxes, areas, selScore);
  hipLaunchKernelGGL(k_mask,  dim3(MNMS / 32, NB), dim3(256), 0, stream, boxes, areas, gmask);
  hipLaunchKernelGGL(k_scan,  dim3(NB), dim3(64), 0, stream, gmask, boxes, areas, selScore, out);
}